// Round 3
// baseline (2285.720 us; speedup 1.0000x reference)
//
#include <hip/hip_runtime.h>
#include <stdint.h>

// GRU encoder: B=512, T=512, H=256, IN=2.
// R2: same persistent design as R1 (2 batches/block, 256 blocks, thread t owns
// gate rows {t,256+t,512+t}, fp16 W, v_dot2_f32_f16) but W registers are
// PINNED via empty inline asm so the RA cannot rematerialize the loads into
// the step loop (R1: VGPR=212 -> W was re-streamed from L2 every step at
// 1 wave/SIMD latency exposure). Batch0/batch1 inner loops merged for ILP.

typedef _Float16 half2_t __attribute__((ext_vector_type(2)));

#define BB 512
#define TT 512
#define HH 256
#define G3 768
#define K2 128   // half2 pairs along K
#define Q4 32    // uint4 groups along K (4 half2 = 8 halves each)

__device__ __forceinline__ float fdot2(uint32_t a, uint32_t b, float c) {
    return __builtin_amdgcn_fdot2(__builtin_bit_cast(half2_t, a),
                                  __builtin_bit_cast(half2_t, b), c, false);
}

// Wq4[(g*Q4 + q)*HH + i] = 8 halves of W_hh[g*256 + i][8q .. 8q+7]
__global__ void prep_pack(const float* __restrict__ Whh, uint4* __restrict__ Wq4) {
    int n = blockIdx.x * blockDim.x + threadIdx.x;   // [0, 24576)
    int i = n & (HH - 1);
    int rest = n >> 8;           // [0, 96)
    int q = rest & (Q4 - 1);
    int g = rest >> 5;
    const float* src = Whh + ((size_t)(g * HH + i)) * HH + 8 * q;
    uint4 o;
    o.x = __builtin_bit_cast(uint32_t, half2_t{(_Float16)src[0], (_Float16)src[1]});
    o.y = __builtin_bit_cast(uint32_t, half2_t{(_Float16)src[2], (_Float16)src[3]});
    o.z = __builtin_bit_cast(uint32_t, half2_t{(_Float16)src[4], (_Float16)src[5]});
    o.w = __builtin_bit_cast(uint32_t, half2_t{(_Float16)src[6], (_Float16)src[7]});
    Wq4[(g * Q4 + q) * HH + i] = o;
}

__device__ __forceinline__ float sigmoid_f(float x) {
    return __builtin_amdgcn_rcpf(1.f + __expf(-x));
}
__device__ __forceinline__ float tanh_f(float x) {
    x = fminf(fmaxf(x, -15.f), 15.f);
    float e = __expf(-2.f * x);
    return (1.f - e) * __builtin_amdgcn_rcpf(1.f + e);
}

__global__ void __launch_bounds__(256, 1)
gru_persist(const float* __restrict__ x,        // [B,T,2]
            const int* __restrict__ len,        // [B]
            const float* __restrict__ h0,       // [B,H]
            const float* __restrict__ Wih,      // [768,2]
            const float* __restrict__ bih,      // [768]
            const float* __restrict__ bhh,      // [768]
            const uint4* __restrict__ Wq4,      // packed fp16 W_hh
            float* __restrict__ out)            // [B,H]
{
    __shared__ __align__(16) _Float16 hsh[2][HH];
    const int t  = threadIdx.x;
    const int b0 = blockIdx.x * 2;
    const int b1 = b0 + 1;

    // ---- W_hh rows {t, 256+t, 512+t}: 384 dwords, PINNED in VGPRs ----
    uint32_t wr[3][K2];
    #pragma unroll
    for (int g = 0; g < 3; ++g) {
        #pragma unroll
        for (int q = 0; q < Q4; ++q) {
            const uint4 u = Wq4[(g * Q4 + q) * HH + t];   // lane-contiguous 16B
            wr[g][4*q+0] = u.x;
            wr[g][4*q+1] = u.y;
            wr[g][4*q+2] = u.z;
            wr[g][4*q+3] = u.w;
        }
    }
    // Opaque defs: not rematerializable -> RA must keep these live in VGPRs.
    #pragma unroll
    for (int g = 0; g < 3; ++g)
        #pragma unroll
        for (int k = 0; k < K2; ++k)
            asm volatile("" : "+v"(wr[g][k]));

    float hp0 = h0[b0 * HH + t];
    float hp1 = h0[b1 * HH + t];
    hsh[0][t] = (_Float16)hp0;
    hsh[1][t] = (_Float16)hp1;

    const int gR = t, gZ = HH + t, gN = 2 * HH + t;
    const float wR0 = Wih[2*gR], wR1 = Wih[2*gR+1];
    const float wZ0 = Wih[2*gZ], wZ1 = Wih[2*gZ+1];
    const float wN0 = Wih[2*gN], wN1 = Wih[2*gN+1];
    const float cR = bih[gR] + bhh[gR];
    const float cZ = bih[gZ] + bhh[gZ];
    const float cN = bih[gN];
    const float dN = bhh[gN];
    const int l0 = len[b0];
    const int l1 = len[b1];
    const int lmax = l0 > l1 ? l0 : l1;
    const float* xb0 = x + (size_t)b0 * TT * 2;
    const float* xb1 = x + (size_t)b1 * TT * 2;

    __syncthreads();

    #pragma unroll 1
    for (int s = 0; s < lmax; ++s) {
        const float x00 = xb0[2*s], x01 = xb0[2*s+1];
        const float x10 = xb1[2*s], x11 = xb1[2*s+1];

        float aR0 = 0.f, aZ0 = 0.f, aN0 = 0.f;
        float aR1 = 0.f, aZ1 = 0.f, aN1 = 0.f;

        const uint4* hq0 = (const uint4*)hsh[0];
        const uint4* hq1 = (const uint4*)hsh[1];
        #pragma unroll
        for (int q = 0; q < Q4; ++q) {
            const uint4 h0v = hq0[q];    // ds_read_b128, all-lane broadcast
            const uint4 h1v = hq1[q];
            aR0 = fdot2(wr[0][4*q+0], h0v.x, aR0);
            aZ0 = fdot2(wr[1][4*q+0], h0v.x, aZ0);
            aN0 = fdot2(wr[2][4*q+0], h0v.x, aN0);
            aR1 = fdot2(wr[0][4*q+0], h1v.x, aR1);
            aZ1 = fdot2(wr[1][4*q+0], h1v.x, aZ1);
            aN1 = fdot2(wr[2][4*q+0], h1v.x, aN1);
            aR0 = fdot2(wr[0][4*q+1], h0v.y, aR0);
            aZ0 = fdot2(wr[1][4*q+1], h0v.y, aZ0);
            aN0 = fdot2(wr[2][4*q+1], h0v.y, aN0);
            aR1 = fdot2(wr[0][4*q+1], h1v.y, aR1);
            aZ1 = fdot2(wr[1][4*q+1], h1v.y, aZ1);
            aN1 = fdot2(wr[2][4*q+1], h1v.y, aN1);
            aR0 = fdot2(wr[0][4*q+2], h0v.z, aR0);
            aZ0 = fdot2(wr[1][4*q+2], h0v.z, aZ0);
            aN0 = fdot2(wr[2][4*q+2], h0v.z, aN0);
            aR1 = fdot2(wr[0][4*q+2], h1v.z, aR1);
            aZ1 = fdot2(wr[1][4*q+2], h1v.z, aZ1);
            aN1 = fdot2(wr[2][4*q+2], h1v.z, aN1);
            aR0 = fdot2(wr[0][4*q+3], h0v.w, aR0);
            aZ0 = fdot2(wr[1][4*q+3], h0v.w, aZ0);
            aN0 = fdot2(wr[2][4*q+3], h0v.w, aN0);
            aR1 = fdot2(wr[0][4*q+3], h1v.w, aR1);
            aZ1 = fdot2(wr[1][4*q+3], h1v.w, aZ1);
            aN1 = fdot2(wr[2][4*q+3], h1v.w, aN1);
        }

        // gates
        const float r0 = sigmoid_f(aR0 + fmaf(x00, wR0, fmaf(x01, wR1, cR)));
        const float z0 = sigmoid_f(aZ0 + fmaf(x00, wZ0, fmaf(x01, wZ1, cZ)));
        const float n0 = tanh_f(fmaf(x00, wN0, fmaf(x01, wN1, cN)) + r0 * (aN0 + dN));
        const float r1 = sigmoid_f(aR1 + fmaf(x10, wR0, fmaf(x11, wR1, cR)));
        const float z1 = sigmoid_f(aZ1 + fmaf(x10, wZ0, fmaf(x11, wZ1, cZ)));
        const float n1 = tanh_f(fmaf(x10, wN0, fmaf(x11, wN1, cN)) + r1 * (aN1 + dN));

        const float hn0 = fmaf(z0, hp0 - n0, n0);   // (1-z)n + z h
        const float hn1 = fmaf(z1, hp1 - n1, n1);

        __syncthreads();               // all reads of hsh done
        if (s < l0) {
            hsh[0][t] = (_Float16)hn0;
            hp0 = hn0;
            if (s == l0 - 1) out[b0 * HH + t] = hn0;
        }
        if (s < l1) {
            hsh[1][t] = (_Float16)hn1;
            hp1 = hn1;
            if (s == l1 - 1) out[b1 * HH + t] = hn1;
        }
        __syncthreads();               // h_new visible before next step
    }
}

extern "C" void kernel_launch(void* const* d_in, const int* in_sizes, int n_in,
                              void* d_out, int out_size, void* d_ws, size_t ws_size,
                              hipStream_t stream) {
    const float* x    = (const float*)d_in[0];
    const int*   lenp = (const int*)d_in[1];
    const float* h0   = (const float*)d_in[2];
    const float* Wih  = (const float*)d_in[3];
    const float* Whh  = (const float*)d_in[4];
    const float* bih  = (const float*)d_in[5];
    const float* bhh  = (const float*)d_in[6];
    float* out = (float*)d_out;

    uint4* Wq4 = (uint4*)d_ws;   // 384 KB scratch

    prep_pack<<<G3 * Q4 / 256, 256, 0, stream>>>(Whh, Wq4);
    gru_persist<<<BB / 2, 256, 0, stream>>>(x, lenp, h0, Wih, bih, bhh, Wq4, out);
}

// Round 4
// 1078.698 us; speedup vs baseline: 2.1190x; 2.1190x over previous
//
#include <hip/hip_runtime.h>
#include <stdint.h>

// GRU encoder: B=512, T=512, H=256, IN=2.
// R3: K-split persistent design. 256 blocks x 512 threads (8 waves, 2/SIMD).
// Thread (t, kh=tid>>8) holds fp16 W_hh rows {t,256+t,512+t} for K-half kh:
// 192 dwords, pinned in arch VGPRs (R2 lesson: 384 > 256-arch-VGPR cap ->
// scratch spill). Each step: both halves compute partial v_dot2_f32_f16 sums
// from an LDS fp16 h mirror; kh=1 ships 3 float2 partials through LDS; kh=0
// reduces, computes gates, updates h. 2 barriers/step.

typedef _Float16 half2_t __attribute__((ext_vector_type(2)));

#define BB 512
#define TT 512
#define HH 256
#define G3 768
#define Q4 32    // uint4 groups along full K (8 halves each)

__device__ __forceinline__ float fdot2(uint32_t a, uint32_t b, float c) {
    return __builtin_amdgcn_fdot2(__builtin_bit_cast(half2_t, a),
                                  __builtin_bit_cast(half2_t, b), c, false);
}

// Wq4[(g*32 + qq)*HH + i] = 8 halves of W_hh[g*256 + i][8qq .. 8qq+7]
__global__ void prep_pack(const float* __restrict__ Whh, uint4* __restrict__ Wq4) {
    int n = blockIdx.x * blockDim.x + threadIdx.x;   // [0, 24576)
    int i = n & (HH - 1);
    int rest = n >> 8;           // [0, 96)
    int qq = rest & (Q4 - 1);
    int g = rest >> 5;
    const float* src = Whh + ((size_t)(g * HH + i)) * HH + 8 * qq;
    uint4 o;
    o.x = __builtin_bit_cast(uint32_t, half2_t{(_Float16)src[0], (_Float16)src[1]});
    o.y = __builtin_bit_cast(uint32_t, half2_t{(_Float16)src[2], (_Float16)src[3]});
    o.z = __builtin_bit_cast(uint32_t, half2_t{(_Float16)src[4], (_Float16)src[5]});
    o.w = __builtin_bit_cast(uint32_t, half2_t{(_Float16)src[6], (_Float16)src[7]});
    Wq4[(g * Q4 + qq) * HH + i] = o;
}

__device__ __forceinline__ float sigmoid_f(float x) {
    return __builtin_amdgcn_rcpf(1.f + __expf(-x));
}
__device__ __forceinline__ float tanh_f(float x) {
    x = fminf(fmaxf(x, -15.f), 15.f);
    float e = __expf(-2.f * x);
    return (1.f - e) * __builtin_amdgcn_rcpf(1.f + e);
}

__global__ void __launch_bounds__(512, 2)
gru_persist(const float* __restrict__ x,        // [B,T,2]
            const int* __restrict__ len,        // [B]
            const float* __restrict__ h0,       // [B,H]
            const float* __restrict__ Wih,      // [768,2]
            const float* __restrict__ bih,      // [768]
            const float* __restrict__ bhh,      // [768]
            const uint4* __restrict__ Wq4,      // packed fp16 W_hh
            float* __restrict__ out)            // [B,H]
{
    __shared__ __align__(16) _Float16 hsh[2][HH];   // fp16 h mirror, 1 KB
    __shared__ __align__(8)  float2   part[3][HH];  // khalf1 partials, 6 KB
    const int tid = threadIdx.x;
    const int t   = tid & (HH - 1);   // element / gate-row index
    const int kh  = tid >> 8;         // K-half: 0 -> k[0,128), 1 -> k[128,256)
    const int b0 = blockIdx.x * 2;
    const int b1 = b0 + 1;

    // ---- W_hh rows {t,256+t,512+t}, K-half kh: 48 uint4 = 192 dwords ----
    uint32_t wr[3][64];
    #pragma unroll
    for (int g = 0; g < 3; ++g) {
        #pragma unroll
        for (int q = 0; q < 16; ++q) {
            const uint4 u = Wq4[(g * Q4 + kh * 16 + q) * HH + t];
            wr[g][4*q+0] = u.x;
            wr[g][4*q+1] = u.y;
            wr[g][4*q+2] = u.z;
            wr[g][4*q+3] = u.w;
        }
    }
    // Opaque defs: keep live in VGPRs (192 fits the 256 arch-VGPR cap).
    #pragma unroll
    for (int g = 0; g < 3; ++g)
        #pragma unroll
        for (int k = 0; k < 64; ++k)
            asm volatile("" : "+v"(wr[g][k]));

    float hp0 = h0[b0 * HH + t];
    float hp1 = h0[b1 * HH + t];
    if (kh == 0) {
        hsh[0][t] = (_Float16)hp0;
        hsh[1][t] = (_Float16)hp1;
    }

    const int gR = t, gZ = HH + t, gN = 2 * HH + t;
    const float wR0 = Wih[2*gR], wR1 = Wih[2*gR+1];
    const float wZ0 = Wih[2*gZ], wZ1 = Wih[2*gZ+1];
    const float wN0 = Wih[2*gN], wN1 = Wih[2*gN+1];
    const float cR = bih[gR] + bhh[gR];
    const float cZ = bih[gZ] + bhh[gZ];
    const float cN = bih[gN];
    const float dN = bhh[gN];
    const int l0 = len[b0];
    const int l1 = len[b1];
    const int lmax = l0 > l1 ? l0 : l1;
    const float* xb0 = x + (size_t)b0 * TT * 2;
    const float* xb1 = x + (size_t)b1 * TT * 2;

    __syncthreads();

    #pragma unroll 1
    for (int s = 0; s < lmax; ++s) {
        float aR0 = 0.f, aZ0 = 0.f, aN0 = 0.f;
        float aR1 = 0.f, aZ1 = 0.f, aN1 = 0.f;

        const uint4* hq0 = ((const uint4*)hsh[0]) + kh * 16;
        const uint4* hq1 = ((const uint4*)hsh[1]) + kh * 16;
        #pragma unroll
        for (int q = 0; q < 16; ++q) {
            const uint4 h0v = hq0[q];   // ds_read_b128, wave-uniform broadcast
            const uint4 h1v = hq1[q];
            aR0 = fdot2(wr[0][4*q+0], h0v.x, aR0);
            aZ0 = fdot2(wr[1][4*q+0], h0v.x, aZ0);
            aN0 = fdot2(wr[2][4*q+0], h0v.x, aN0);
            aR1 = fdot2(wr[0][4*q+0], h1v.x, aR1);
            aZ1 = fdot2(wr[1][4*q+0], h1v.x, aZ1);
            aN1 = fdot2(wr[2][4*q+0], h1v.x, aN1);
            aR0 = fdot2(wr[0][4*q+1], h0v.y, aR0);
            aZ0 = fdot2(wr[1][4*q+1], h0v.y, aZ0);
            aN0 = fdot2(wr[2][4*q+1], h0v.y, aN0);
            aR1 = fdot2(wr[0][4*q+1], h1v.y, aR1);
            aZ1 = fdot2(wr[1][4*q+1], h1v.y, aZ1);
            aN1 = fdot2(wr[2][4*q+1], h1v.y, aN1);
            aR0 = fdot2(wr[0][4*q+2], h0v.z, aR0);
            aZ0 = fdot2(wr[1][4*q+2], h0v.z, aZ0);
            aN0 = fdot2(wr[2][4*q+2], h0v.z, aN0);
            aR1 = fdot2(wr[0][4*q+2], h1v.z, aR1);
            aZ1 = fdot2(wr[1][4*q+2], h1v.z, aZ1);
            aN1 = fdot2(wr[2][4*q+2], h1v.z, aN1);
            aR0 = fdot2(wr[0][4*q+3], h0v.w, aR0);
            aZ0 = fdot2(wr[1][4*q+3], h0v.w, aZ0);
            aN0 = fdot2(wr[2][4*q+3], h0v.w, aN0);
            aR1 = fdot2(wr[0][4*q+3], h1v.w, aR1);
            aZ1 = fdot2(wr[1][4*q+3], h1v.w, aZ1);
            aN1 = fdot2(wr[2][4*q+3], h1v.w, aN1);
        }

        if (kh) {   // ship partials to the reducing half
            part[0][t] = float2{aR0, aR1};
            part[1][t] = float2{aZ0, aZ1};
            part[2][t] = float2{aN0, aN1};
        }
        __syncthreads();   // partials visible; all hsh reads complete

        if (!kh) {
            const float2 pR = part[0][t];
            const float2 pZ = part[1][t];
            const float2 pN = part[2][t];
            aR0 += pR.x; aR1 += pR.y;
            aZ0 += pZ.x; aZ1 += pZ.y;
            aN0 += pN.x; aN1 += pN.y;

            const float x00 = xb0[2*s], x01 = xb0[2*s+1];
            const float x10 = xb1[2*s], x11 = xb1[2*s+1];

            const float r0 = sigmoid_f(aR0 + fmaf(x00, wR0, fmaf(x01, wR1, cR)));
            const float z0 = sigmoid_f(aZ0 + fmaf(x00, wZ0, fmaf(x01, wZ1, cZ)));
            const float n0 = tanh_f(fmaf(x00, wN0, fmaf(x01, wN1, cN)) + r0 * (aN0 + dN));
            const float r1 = sigmoid_f(aR1 + fmaf(x10, wR0, fmaf(x11, wR1, cR)));
            const float z1 = sigmoid_f(aZ1 + fmaf(x10, wZ0, fmaf(x11, wZ1, cZ)));
            const float n1 = tanh_f(fmaf(x10, wN0, fmaf(x11, wN1, cN)) + r1 * (aN1 + dN));

            const float hn0 = fmaf(z0, hp0 - n0, n0);   // (1-z)n + z h
            const float hn1 = fmaf(z1, hp1 - n1, n1);

            if (s < l0) {
                hsh[0][t] = (_Float16)hn0;
                hp0 = hn0;
                if (s == l0 - 1) out[b0 * HH + t] = hn0;
            }
            if (s < l1) {
                hsh[1][t] = (_Float16)hn1;
                hp1 = hn1;
                if (s == l1 - 1) out[b1 * HH + t] = hn1;
            }
        }
        __syncthreads();   // h_new visible before next step's reads
    }
}

extern "C" void kernel_launch(void* const* d_in, const int* in_sizes, int n_in,
                              void* d_out, int out_size, void* d_ws, size_t ws_size,
                              hipStream_t stream) {
    const float* x    = (const float*)d_in[0];
    const int*   lenp = (const int*)d_in[1];
    const float* h0   = (const float*)d_in[2];
    const float* Wih  = (const float*)d_in[3];
    const float* Whh  = (const float*)d_in[4];
    const float* bih  = (const float*)d_in[5];
    const float* bhh  = (const float*)d_in[6];
    float* out = (float*)d_out;

    uint4* Wq4 = (uint4*)d_ws;   // 384 KB scratch

    prep_pack<<<G3 * Q4 / 256, 256, 0, stream>>>(Whh, Wq4);
    gru_persist<<<BB / 2, 512, 0, stream>>>(x, lenp, h0, Wih, bih, bhh, Wq4, out);
}

// Round 6
// 834.067 us; speedup vs baseline: 2.7405x; 1.2933x over previous
//
#include <hip/hip_runtime.h>
#include <stdint.h>

// GRU encoder B=512,T=512,H=256,IN=2 — R5 = R4 with the dead-line compile fix.
// 256 blocks x 512 thr (8 waves, 2/SIMD). W_hh fp16 lives in 192 AGPRs/thread
// as v_mfma_f32_16x16x32_f16 B-fragments (MFMA reads AGPR natively -> no
// accvgpr round-trip, R3's tax). A-operand = h fp16 (2 batches in rows 0/1)
// broadcast from LDS. Wave w owns gate rows [96w,96w+96). D(f32) rows 0/1 ->
// LDS -> 512 gate-threads do fp32 sigmoid/tanh update, h fp32 master in reg.

typedef _Float16 v8h  __attribute__((ext_vector_type(8)));
typedef float    f32x4 __attribute__((ext_vector_type(4)));

#define BB 512
#define TT 512
#define HH 256
#define G3 768
#define NT 48    // 768/16 col tiles
#define KT 8     // 256/32 k tiles

// Wp4[(ct*KT + kt)*64 + lane] = 8 halves W_hh[16ct + (lane&15)][32kt + (lane>>4)*8 + j]
__global__ void prep_pack(const float* __restrict__ Whh, uint4* __restrict__ Wp4) {
    int n = blockIdx.x * blockDim.x + threadIdx.x;   // [0, 24576)
    int lane = n & 63;
    int kt = (n >> 6) & (KT - 1);
    int ct = n >> 9;
    int row = 16 * ct + (lane & 15);
    int k0  = 32 * kt + (lane >> 4) * 8;
    const float* src = Whh + (size_t)row * HH + k0;
    v8h v;
    #pragma unroll
    for (int j = 0; j < 8; ++j) v[j] = (_Float16)src[j];
    Wp4[n] = __builtin_bit_cast(uint4, v);
}

__device__ __forceinline__ float sigmoid_f(float x) {
    return __builtin_amdgcn_rcpf(1.f + __expf(-x));
}
__device__ __forceinline__ float tanh_f(float x) {
    x = fminf(fmaxf(x, -15.f), 15.f);
    float e = __expf(-2.f * x);
    return (1.f - e) * __builtin_amdgcn_rcpf(1.f + e);
}

__global__ void __launch_bounds__(512, 2)
gru_persist(const float* __restrict__ x,        // [B,T,2]
            const int* __restrict__ len,        // [B]
            const float* __restrict__ h0,       // [B,H]
            const float* __restrict__ Wih,      // [768,2]
            const float* __restrict__ bih,      // [768]
            const float* __restrict__ bhh,      // [768]
            const uint4* __restrict__ Wp4,      // MFMA-fragment-packed fp16 W_hh
            float* __restrict__ out)            // [B,H]
{
    __shared__ __align__(16) _Float16 h16[2][HH];   // 1 KB fp16 h mirror
    __shared__ __align__(8)  float2   dots[G3];     // 6 KB (batch0,batch1) per gate row
    __shared__ float4 cst4[HH];                     // cR,cZ,cN,dN
    __shared__ float4 wx4[HH];                      // wR0,wR1,wZ0,wZ1
    __shared__ float2 wn2[HH];                      // wN0,wN1

    const int tid  = threadIdx.x;
    const int lane = tid & 63;
    const int w    = tid >> 6;          // wave 0..7
    const int b0   = blockIdx.x * 2;

    // ---- W B-fragments: 6 tiles x 8 k-tiles x v8h, pinned in AGPRs ----
    v8h wfr[6][KT];
    #pragma unroll
    for (int c = 0; c < 6; ++c)
        #pragma unroll
        for (int kt = 0; kt < KT; ++kt)
            wfr[c][kt] = __builtin_bit_cast(v8h, Wp4[((6 * w + c) * KT + kt) * 64 + lane]);
    #pragma unroll
    for (int c = 0; c < 6; ++c)
        #pragma unroll
        for (int kt = 0; kt < KT; ++kt)
            asm volatile("" : "+a"(wfr[c][kt]));    // AGPR-resident, not remat

    // ---- per-element constants into LDS (saves ~10 VGPR/thread) ----
    if (tid < HH) {
        const int e2 = tid;
        cst4[e2] = float4{bih[e2] + bhh[e2], bih[HH + e2] + bhh[HH + e2],
                          bih[2 * HH + e2], bhh[2 * HH + e2]};
        wx4[e2] = float4{Wih[2 * e2], Wih[2 * e2 + 1],
                         Wih[2 * (HH + e2)], Wih[2 * (HH + e2) + 1]};
        wn2[e2] = float2{Wih[2 * (2 * HH + e2)], Wih[2 * (2 * HH + e2) + 1]};
    }

    // ---- gate-thread state: element e, batch b ----
    const int e = tid & (HH - 1);
    const int b = tid >> 8;
    float hp = h0[(b0 + b) * HH + e];   // fp32 master h
    h16[b][e] = (_Float16)hp;
    const int myl = len[b0 + b];
    const int l0 = len[b0], l1 = len[b0 + 1];
    const int lm = l0 > l1 ? l0 : l1;
    const float* xb = x + (size_t)(b0 + b) * TT * 2;

    // A-fragment LDS source: row m=lane&15 -> batch m&1, k = kt*32 + (lane>>4)*8
    const _Float16* aptr = &h16[(lane & 15) & 1][(lane >> 4) * 8];

    __syncthreads();

    #pragma unroll 1
    for (int s = 0; s < lm; ++s) {
        // ---------- phase A: gh = h @ W^T via MFMA ----------
        #pragma unroll
        for (int pass = 0; pass < 2; ++pass) {
            f32x4 d0 = {0.f, 0.f, 0.f, 0.f};
            f32x4 d1 = {0.f, 0.f, 0.f, 0.f};
            f32x4 d2 = {0.f, 0.f, 0.f, 0.f};
            #pragma unroll
            for (int kt = 0; kt < KT; ++kt) {
                const v8h a = *(const v8h*)(aptr + kt * 32);   // ds_read_b128 broadcast
                d0 = __builtin_amdgcn_mfma_f32_16x16x32_f16(a, wfr[3 * pass + 0][kt], d0, 0, 0, 0);
                d1 = __builtin_amdgcn_mfma_f32_16x16x32_f16(a, wfr[3 * pass + 1][kt], d1, 0, 0, 0);
                d2 = __builtin_amdgcn_mfma_f32_16x16x32_f16(a, wfr[3 * pass + 2][kt], d2, 0, 0, 0);
            }
            // D rows 0/1 = batches 0/1 (C/D: col=lane&15, row=(lane>>4)*4+reg)
            if (lane < 16) {
                const int nb = 96 * w + 48 * pass + lane;
                dots[nb]      = float2{d0[0], d0[1]};
                dots[nb + 16] = float2{d1[0], d1[1]};
                dots[nb + 32] = float2{d2[0], d2[1]};
            }
        }
        __syncthreads();   // dots visible; h16 reads done

        // ---------- phase B: gates + h update (512 threads) ----------
        const float aR = ((const float*)&dots[e])[b];
        const float aZ = ((const float*)&dots[HH + e])[b];
        const float aN = ((const float*)&dots[2 * HH + e])[b];
        const float4 cc = cst4[e];
        const float4 wx = wx4[e];
        const float2 wn = wn2[e];
        const float2 xv = *(const float2*)(xb + 2 * s);

        const float r = sigmoid_f(aR + fmaf(xv.x, wx.x, fmaf(xv.y, wx.y, cc.x)));
        const float z = sigmoid_f(aZ + fmaf(xv.x, wx.z, fmaf(xv.y, wx.w, cc.y)));
        const float n = tanh_f(fmaf(xv.x, wn.x, fmaf(xv.y, wn.y, cc.z)) + r * (aN + cc.w));
        const float hn = fmaf(z, hp - n, n);    // (1-z)n + z h

        if (s < myl) {
            hp = hn;
            h16[b][e] = (_Float16)hn;
            if (s == myl - 1) out[(b0 + b) * HH + e] = hn;
        }
        __syncthreads();   // h16 update visible for next step's A
    }
}

extern "C" void kernel_launch(void* const* d_in, const int* in_sizes, int n_in,
                              void* d_out, int out_size, void* d_ws, size_t ws_size,
                              hipStream_t stream) {
    const float* x    = (const float*)d_in[0];
    const int*   lenp = (const int*)d_in[1];
    const float* h0   = (const float*)d_in[2];
    const float* Wih  = (const float*)d_in[3];
    const float* Whh  = (const float*)d_in[4];
    const float* bih  = (const float*)d_in[5];
    const float* bhh  = (const float*)d_in[6];
    float* out = (float*)d_out;

    uint4* Wp4 = (uint4*)d_ws;   // 384 KB scratch

    prep_pack<<<NT * KT * 64 / 256, 256, 0, stream>>>(Whh, Wp4);
    gru_persist<<<BB / 2, 512, 0, stream>>>(x, lenp, h0, Wih, bih, bhh, Wp4, out);
}

// Round 7
// 655.863 us; speedup vs baseline: 3.4851x; 1.2717x over previous
//
#include <hip/hip_runtime.h>
#include <stdint.h>

// GRU encoder B=512,T=512,H=256,IN=2 — R6: single-barrier MFMA persistent.
// 256 blocks x 512 thr (8 waves, 2/SIMD). Register budget is THE constraint:
// 512-reg unified file / 2 waves = 256/thread. W fp16 = 192 AGPR (pinned
// "+a"), everything else must fit ~64 arch VGPRs (R5 used 128 -> 64 dwords of
// W spilled to scratch-L2, ~8 MB WRITE_SIZE, +2000 cyc/step).
// Wave w owns elements [32w,32w+32): tiles ct={2w,2w+1,16+2w,16+2w+1,32+2w,
// 32+2w+1} so r/z/n for its elements land in-wave. Gates on lanes 0-31 after
// shfl_up(16) redistribution. h16 mirror double-buffered -> 1 barrier/step.

typedef _Float16 v8h  __attribute__((ext_vector_type(8)));
typedef float    f32x4 __attribute__((ext_vector_type(4)));

#define BB 512
#define TT 512
#define HH 256
#define NT 48    // 768/16 col tiles
#define KT 8     // 256/32 k tiles

// Wp4[(ct*KT + kt)*64 + lane] = 8 halves W_hh[16ct + (lane&15)][32kt + (lane>>4)*8 + j]
__global__ void prep_pack(const float* __restrict__ Whh, uint4* __restrict__ Wp4) {
    int n = blockIdx.x * blockDim.x + threadIdx.x;   // [0, 24576)
    int lane = n & 63;
    int kt = (n >> 6) & (KT - 1);
    int ct = n >> 9;
    int row = 16 * ct + (lane & 15);
    int k0  = 32 * kt + (lane >> 4) * 8;
    const float* src = Whh + (size_t)row * HH + k0;
    v8h v;
    #pragma unroll
    for (int j = 0; j < 8; ++j) v[j] = (_Float16)src[j];
    Wp4[n] = __builtin_bit_cast(uint4, v);
}

__device__ __forceinline__ float sigmoid_f(float x) {
    return __builtin_amdgcn_rcpf(1.f + __expf(-x));
}
__device__ __forceinline__ float tanh_f(float x) {
    x = fminf(fmaxf(x, -15.f), 15.f);
    float e = __expf(-2.f * x);
    return (1.f - e) * __builtin_amdgcn_rcpf(1.f + e);
}

__global__ void __launch_bounds__(512, 2)
gru_persist(const float* __restrict__ x,        // [B,T,2]
            const int* __restrict__ len,        // [B]
            const float* __restrict__ h0,       // [B,H]
            const float* __restrict__ Wih,      // [768,2]
            const float* __restrict__ bih,      // [768]
            const float* __restrict__ bhh,      // [768]
            const uint4* __restrict__ Wp4,      // MFMA-fragment-packed fp16 W_hh
            float* __restrict__ out)            // [B,H]
{
    __shared__ __align__(16) _Float16 h16[2][2][HH];   // [buf][batch][e], 2 KB
    const int tid  = threadIdx.x;
    const int lane = tid & 63;
    const int w    = tid >> 6;          // wave 0..7
    const int b0   = blockIdx.x * 2;

    // ---- W B-fragments for this wave's 6 tiles, pinned in AGPRs ----
    v8h wfr[6][KT];
    {
        const int cts[6] = {2*w, 2*w+1, 16+2*w, 16+2*w+1, 32+2*w, 32+2*w+1};
        #pragma unroll
        for (int c = 0; c < 6; ++c)
            #pragma unroll
            for (int kt = 0; kt < KT; ++kt)
                wfr[c][kt] = __builtin_bit_cast(v8h, Wp4[(cts[c] * KT + kt) * 64 + lane]);
    }
    #pragma unroll
    for (int c = 0; c < 6; ++c)
        #pragma unroll
        for (int kt = 0; kt < KT; ++kt)
            asm volatile("" : "+a"(wfr[c][kt]));    // AGPR-resident, not remat

    // ---- gate-lane state: element e = 32w + (lane&31), both batches ----
    const int e = 32 * w + (lane & 31);             // valid duty for lanes 0..31
    float cR = bih[e] + bhh[e];
    float cZ = bih[HH + e] + bhh[HH + e];
    float cN = bih[2 * HH + e];
    float dN = bhh[2 * HH + e];
    float wR0 = Wih[2 * e],            wR1 = Wih[2 * e + 1];
    float wZ0 = Wih[2 * (HH + e)],     wZ1 = Wih[2 * (HH + e) + 1];
    float wN0 = Wih[2 * (2 * HH + e)], wN1 = Wih[2 * (2 * HH + e) + 1];
    float hp0 = h0[b0 * HH + e];
    float hp1 = h0[(b0 + 1) * HH + e];
    // keep loop-invariants in VGPRs (R1 lesson: RA remats invariant loads)
    asm volatile("" : "+v"(cR), "+v"(cZ), "+v"(cN), "+v"(dN));
    asm volatile("" : "+v"(wR0), "+v"(wR1), "+v"(wZ0), "+v"(wZ1));
    asm volatile("" : "+v"(wN0), "+v"(wN1));

    if (lane < 32) {
        h16[0][0][e] = (_Float16)hp0;
        h16[0][1][e] = (_Float16)hp1;
    }

    const int l0 = len[b0], l1 = len[b0 + 1];
    const int lm = l0 > l1 ? l0 : l1;
    const float* xb0 = x + (size_t)b0 * TT * 2;
    const float* xb1 = x + (size_t)(b0 + 1) * TT * 2;

    // A-fragment source: row m=lane&15 -> batch m&1, k = kt*32 + (lane>>4)*8
    const _Float16* abase = &h16[0][(lane & 15) & 1][(lane >> 4) * 8];

    __syncthreads();

    #pragma unroll 1
    for (int s = 0; s < lm; ++s) {
        // wave-uniform x loads (SGPR path), issued before the MFMA phase
        const float2 xv0 = *(const float2*)(xb0 + 2 * s);
        const float2 xv1 = *(const float2*)(xb1 + 2 * s);

        const _Float16* ap = abase + (s & 1) * (2 * HH);   // h16 ping-pong
        f32x4 d0 = {0.f,0.f,0.f,0.f}, d1 = {0.f,0.f,0.f,0.f}, d2 = {0.f,0.f,0.f,0.f};
        f32x4 d3 = {0.f,0.f,0.f,0.f}, d4 = {0.f,0.f,0.f,0.f}, d5 = {0.f,0.f,0.f,0.f};
        #pragma unroll
        for (int kt = 0; kt < KT; ++kt) {
            const v8h a = *(const v8h*)(ap + kt * 32);     // ds_read_b128 broadcast
            d0 = __builtin_amdgcn_mfma_f32_16x16x32_f16(a, wfr[0][kt], d0, 0, 0, 0);
            d1 = __builtin_amdgcn_mfma_f32_16x16x32_f16(a, wfr[1][kt], d1, 0, 0, 0);
            d2 = __builtin_amdgcn_mfma_f32_16x16x32_f16(a, wfr[2][kt], d2, 0, 0, 0);
            d3 = __builtin_amdgcn_mfma_f32_16x16x32_f16(a, wfr[3][kt], d3, 0, 0, 0);
            d4 = __builtin_amdgcn_mfma_f32_16x16x32_f16(a, wfr[4][kt], d4, 0, 0, 0);
            d5 = __builtin_amdgcn_mfma_f32_16x16x32_f16(a, wfr[5][kt], d5, 0, 0, 0);
        }

        // D layout: col=lane&15, rows 0/1 (regs 0/1 on lanes 0-15) = batches.
        // Move odd-tile results (elements 32w+16+l) to lanes 16-31.
        const float sR0 = __shfl_up(d1[0], 16), sR1 = __shfl_up(d1[1], 16);
        const float sZ0 = __shfl_up(d3[0], 16), sZ1 = __shfl_up(d3[1], 16);
        const float sN0 = __shfl_up(d5[0], 16), sN1 = __shfl_up(d5[1], 16);
        const bool hi = (lane & 16) != 0;
        const float uR0 = hi ? sR0 : d0[0], uR1 = hi ? sR1 : d0[1];
        const float uZ0 = hi ? sZ0 : d2[0], uZ1 = hi ? sZ1 : d2[1];
        const float uN0 = hi ? sN0 : d4[0], uN1 = hi ? sN1 : d4[1];

        if (lane < 32) {
            const float r0 = sigmoid_f(uR0 + fmaf(xv0.x, wR0, fmaf(xv0.y, wR1, cR)));
            const float z0 = sigmoid_f(uZ0 + fmaf(xv0.x, wZ0, fmaf(xv0.y, wZ1, cZ)));
            const float n0 = tanh_f(fmaf(xv0.x, wN0, fmaf(xv0.y, wN1, cN)) + r0 * (uN0 + dN));
            float hn0 = fmaf(z0, hp0 - n0, n0);
            const float r1 = sigmoid_f(uR1 + fmaf(xv1.x, wR0, fmaf(xv1.y, wR1, cR)));
            const float z1 = sigmoid_f(uZ1 + fmaf(xv1.x, wZ0, fmaf(xv1.y, wZ1, cZ)));
            const float n1 = tanh_f(fmaf(xv1.x, wN0, fmaf(xv1.y, wN1, cN)) + r1 * (uN1 + dN));
            float hn1 = fmaf(z1, hp1 - n1, n1);

            hn0 = (s < l0) ? hn0 : hp0;    // freeze finished batches
            hn1 = (s < l1) ? hn1 : hp1;
            const int nb = (s & 1) ^ 1;
            h16[nb][0][e] = (_Float16)hn0;
            h16[nb][1][e] = (_Float16)hn1;
            hp0 = hn0;
            hp1 = hn1;
            if (s == l0 - 1) out[b0 * HH + e] = hn0;
            if (s == l1 - 1) out[(b0 + 1) * HH + e] = hn1;
        }
        __syncthreads();   // new h16 buffer visible for next step's A reads
    }
}

extern "C" void kernel_launch(void* const* d_in, const int* in_sizes, int n_in,
                              void* d_out, int out_size, void* d_ws, size_t ws_size,
                              hipStream_t stream) {
    const float* x    = (const float*)d_in[0];
    const int*   lenp = (const int*)d_in[1];
    const float* h0   = (const float*)d_in[2];
    const float* Wih  = (const float*)d_in[3];
    const float* Whh  = (const float*)d_in[4];
    const float* bih  = (const float*)d_in[5];
    const float* bhh  = (const float*)d_in[6];
    float* out = (float*)d_out;

    uint4* Wp4 = (uint4*)d_ws;   // 384 KB scratch

    prep_pack<<<NT * KT * 64 / 256, 256, 0, stream>>>(Whh, Wp4);
    gru_persist<<<BB / 2, 512, 0, stream>>>(x, lenp, h0, Wih, bih, bhh, Wp4, out);
}